// Round 5
// baseline (251.507 us; speedup 1.0000x reference)
//
#include <hip/hip_runtime.h>
#include <hip/hip_fp16.h>
#include <stdint.h>

#define DIM 256
#define KE  768

typedef _Float16 half8 __attribute__((ext_vector_type(8)));
typedef float floatx4 __attribute__((ext_vector_type(4)));

// Workspace layout (bytes):
//   Xe    : 8192*768 ushort @ 0          (12,582,912)  [xh | xh | xl*2^11]
//   We    : 5376*768 ushort @ 12582912   ( 8,257,536)  [wh | wl*2^11 | wh]
//   wnorm : 5376 float      @ 20840448
//   xnorm : 8192 float      @ 20861952
//   best  : 24576 u64       @ 20894720   (level*8192+row) packed (d2<<32)|idx
#define WS_WE_OFF    12582912
#define WS_WNORM_OFF 20840448
#define WS_XNORM_OFF 20861952
#define WS_BEST_OFF  20894720

// One wave per row: fp32 norm + fp16 hi/lo split into the expanded layouts.
// Blocks 0..95 additionally init best[] (replaces the memset launch).
__global__ __launch_bounds__(256) void conv_kernel(
    const float* __restrict__ x, const float* __restrict__ w1,
    const float* __restrict__ w2, const float* __restrict__ w3,
    ushort* __restrict__ Xe, ushort* __restrict__ We,
    float* __restrict__ wnorm, float* __restrict__ xnorm,
    unsigned long long* __restrict__ best) {
  if (blockIdx.x < 96) best[blockIdx.x * 256 + threadIdx.x] = ~0ull;

  int task = blockIdx.x * 4 + (threadIdx.x >> 6);
  int lane = threadIdx.x & 63;
  const float* src; ushort* dst; float* ndst; int isx;
  if (task < 8192) {
    src = x + (size_t)task * DIM; dst = Xe + (size_t)task * KE;
    ndst = xnorm + task; isx = 1;
  } else {
    int wi = task - 8192;
    if (wi < 256)       src = w1 + (size_t)wi * DIM;
    else if (wi < 1280) src = w2 + (size_t)(wi - 256) * DIM;
    else                src = w3 + (size_t)(wi - 1280) * DIM;
    dst = We + (size_t)wi * KE; ndst = wnorm + wi; isx = 0;
  }
  float4 v = *(const float4*)(src + lane * 4);
  float fv[4] = {v.x, v.y, v.z, v.w};
  float s = fv[0]*fv[0] + fv[1]*fv[1] + fv[2]*fv[2] + fv[3]*fv[3];
  #pragma unroll
  for (int o = 32; o > 0; o >>= 1) s += __shfl_xor(s, o);
  if (lane == 0) *ndst = s;

  ushort h[4], l[4];
  #pragma unroll
  for (int e = 0; e < 4; ++e) {
    __half hh = __float2half(fv[e]);
    float hf = __half2float(hh);
    __half ll = __float2half((fv[e] - hf) * 2048.0f);  // scaled lo: no denorms
    h[e] = __half_as_ushort(hh);
    l[e] = __half_as_ushort(ll);
  }
  ushort4 h4 = make_ushort4(h[0], h[1], h[2], h[3]);
  ushort4 l4 = make_ushort4(l[0], l[1], l[2], l[3]);
  if (isx) {  // [xh | xh | xl2]
    *(ushort4*)(dst + lane * 4)        = h4;
    *(ushort4*)(dst + 256 + lane * 4)  = h4;
    *(ushort4*)(dst + 512 + lane * 4)  = l4;
  } else {    // [wh | wl2 | wh]
    *(ushort4*)(dst + lane * 4)        = h4;
    *(ushort4*)(dst + 256 + lane * 4)  = l4;
    *(ushort4*)(dst + 512 + lane * 4)  = h4;
  }
}

// 128x128 tile MFMA GEMM over K=768 with fused per-row argmin.
// grid.x = 42 col-blocks (2 | 8 | 32 per level), grid.y = 64 row-blocks.
// Pipeline: A-frags are wave-private -> loaded global->reg directly
// (no LDS, no barrier dependency); B double-buffered in LDS with
// global_load_lds issued one full chunk ahead of its barrier.
__global__ __launch_bounds__(256) void gemm_kernel(
    const ushort* __restrict__ Xe, const ushort* __restrict__ We,
    const float* __restrict__ xnorm, const float* __restrict__ wnorm,
    unsigned long long* __restrict__ best) {
  __shared__ __align__(16) ushort Bs[2][128 * 64];  // 2 x 16KB, XOR-swizzled
  __shared__ unsigned long long red[2][128];

  const int cb = blockIdx.x;
  const int r0 = blockIdx.y * 128;
  const int n0 = cb * 128;
  int level, lbase;
  if (cb < 2)       { level = 0; lbase = 0; }
  else if (cb < 10) { level = 1; lbase = 256; }
  else              { level = 2; lbase = 1280; }

  const int t = threadIdx.x;
  const int w = t >> 6;
  const int lane = t & 63;
  const int ln = lane & 15, q = lane >> 4;
  const int wm = (w >> 1) * 64, wn = (w & 1) * 64;

  // B staging address precompute (swizzled chunks; wave-uniform LDS base).
  const int sm = t >> 3;                    // source row 0..31 (+it*32)
  const int sc = (t & 7) ^ (sm & 7);        // swizzled k-chunk
  const int ldst = (t & 192) * 8;           // wave-uniform chunk base *8 halves

  // A fragment base: row = r0 + wm + mt*16 + ln, 16B at k-offset q*8.
  const ushort* abase = Xe + (size_t)(r0 + wm + ln) * KE + q * 8;

  floatx4 acc[4][4];
  #pragma unroll
  for (int i = 0; i < 4; ++i)
    #pragma unroll
    for (int j = 0; j < 4; ++j) acc[i][j] = (floatx4)0.0f;

  half8 a0[4], a1[4];

  // Prologue: stage B chunk0 into Bs[0]; load a-frags (chunk0, s=0).
  #pragma unroll
  for (int it = 0; it < 4; ++it) {
    const ushort* gb = We + (size_t)(n0 + it * 32 + sm) * KE + sc * 8;
    __builtin_amdgcn_global_load_lds(
        (const __attribute__((address_space(1))) void*)gb,
        (__attribute__((address_space(3))) void*)(&Bs[0][it * 2048 + ldst]),
        16, 0, 0);
  }
  #pragma unroll
  for (int mt = 0; mt < 4; ++mt)
    a0[mt] = *(const half8*)(abase + (size_t)mt * 16 * KE);
  __syncthreads();

  for (int i = 0; i < 12; ++i) {
    const int k0 = i * 64;
    if (i == 4) {  // hh phase done: rescale so pre-scaled cross terms match
      #pragma unroll
      for (int ii = 0; ii < 4; ++ii)
        #pragma unroll
        for (int jj = 0; jj < 4; ++jj) acc[ii][jj] *= 2048.0f;
    }
    // Issue a-frags (chunk i, s=1) — wave-private, covered by s=0 compute.
    #pragma unroll
    for (int mt = 0; mt < 4; ++mt)
      a1[mt] = *(const half8*)(abase + (size_t)mt * 16 * KE + k0 + 32);
    // Issue B staging for chunk i+1 into the other buffer (drained by the
    // end-of-iter barrier, a full compute-phase later).
    if (i < 11) {
      #pragma unroll
      for (int it = 0; it < 4; ++it) {
        const ushort* gb =
            We + (size_t)(n0 + it * 32 + sm) * KE + k0 + 64 + sc * 8;
        __builtin_amdgcn_global_load_lds(
            (const __attribute__((address_space(1))) void*)gb,
            (__attribute__((address_space(3))) void*)(
                &Bs[(i + 1) & 1][it * 2048 + ldst]),
            16, 0, 0);
      }
    }
    const ushort* bsrc = Bs[i & 1];
    // s = 0
    {
      half8 b[4];
      #pragma unroll
      for (int nt = 0; nt < 4; ++nt) {
        int n = wn + nt * 16 + ln;
        int pos = n * 8 + (q ^ (n & 7));
        b[nt] = *(const half8*)&bsrc[pos * 8];
      }
      #pragma unroll
      for (int mt = 0; mt < 4; ++mt)
        #pragma unroll
        for (int nt = 0; nt < 4; ++nt)
          acc[mt][nt] = __builtin_amdgcn_mfma_f32_16x16x32_f16(
              a0[mt], b[nt], acc[mt][nt], 0, 0, 0);
    }
    // Prefetch a-frags (chunk i+1, s=0) — used after the barrier.
    if (i < 11) {
      #pragma unroll
      for (int mt = 0; mt < 4; ++mt)
        a0[mt] = *(const half8*)(abase + (size_t)mt * 16 * KE + k0 + 64);
    }
    // s = 1
    {
      half8 b[4];
      #pragma unroll
      for (int nt = 0; nt < 4; ++nt) {
        int n = wn + nt * 16 + ln;
        int pos = n * 8 + ((4 + q) ^ (n & 7));
        b[nt] = *(const half8*)&bsrc[pos * 8];
      }
      #pragma unroll
      for (int mt = 0; mt < 4; ++mt)
        #pragma unroll
        for (int nt = 0; nt < 4; ++nt)
          acc[mt][nt] = __builtin_amdgcn_mfma_f32_16x16x32_f16(
              a1[mt], b[nt], acc[mt][nt], 0, 0, 0);
    }
    __syncthreads();
  }

  // acc = 2^11 * dot. d2 = xn + wn - 2*dot = xn + wn - acc * 2^-10.
  float wnv[4];
  #pragma unroll
  for (int nt = 0; nt < 4; ++nt) wnv[nt] = wnorm[n0 + wn + nt * 16 + ln];

  #pragma unroll
  for (int mt = 0; mt < 4; ++mt) {
    #pragma unroll
    for (int r = 0; r < 4; ++r) {
      int rowl = wm + mt * 16 + q * 4 + r;
      float xnv = xnorm[r0 + rowl];
      unsigned long long bp = ~0ull;
      #pragma unroll
      for (int nt = 0; nt < 4; ++nt) {
        float d2 = fmaxf(xnv + wnv[nt] - acc[mt][nt][r] * 0.0009765625f, 0.0f);
        unsigned col = (unsigned)(n0 + wn + nt * 16 + ln - lbase);
        unsigned long long p =
            ((unsigned long long)__float_as_uint(d2) << 32) | col;
        bp = (p < bp) ? p : bp;
      }
      #pragma unroll
      for (int off = 1; off < 16; off <<= 1) {
        unsigned long long o = __shfl_xor(bp, off);
        bp = (o < bp) ? o : bp;
      }
      if (ln == 0) red[w & 1][rowl] = bp;
    }
  }
  __syncthreads();
  if (t < 128) {
    unsigned long long a = red[0][t], b = red[1][t];
    unsigned long long m = (a < b) ? a : b;
    atomicMin(&best[level * 8192 + r0 + t], m);
  }
}

// One thread per (level,row): unpack best -> coords + q = sqrt(d2).
__global__ __launch_bounds__(256) void finalize_kernel(
    const unsigned long long* __restrict__ best, float* __restrict__ out) {
  int task = blockIdx.x * 256 + threadIdx.x;
  int level = task >> 13;
  int row = task & 8191;
  unsigned side = (level == 0) ? 16u : (level == 1) ? 32u : 64u;
  unsigned long long p = best[task];
  unsigned idx = (unsigned)(p & 0xFFFFFFFFull);
  float d2 = __uint_as_float((unsigned)(p >> 32));
  out[level * 16384 + row * 2 + 0] = (float)(idx / side);
  out[level * 16384 + row * 2 + 1] = (float)(idx % side);
  out[49152 + level * 8192 + row] = sqrtf(d2);
}

extern "C" void kernel_launch(void* const* d_in, const int* in_sizes, int n_in,
                              void* d_out, int out_size, void* d_ws, size_t ws_size,
                              hipStream_t stream) {
  const float* x  = (const float*)d_in[0];
  const float* w1 = (const float*)d_in[1];
  const float* w2 = (const float*)d_in[2];
  const float* w3 = (const float*)d_in[3];
  ushort* Xe = (ushort*)d_ws;
  ushort* We = (ushort*)((char*)d_ws + WS_WE_OFF);
  float* wnorm = (float*)((char*)d_ws + WS_WNORM_OFF);
  float* xnorm = (float*)((char*)d_ws + WS_XNORM_OFF);
  unsigned long long* best = (unsigned long long*)((char*)d_ws + WS_BEST_OFF);

  conv_kernel<<<3392, 256, 0, stream>>>(x, w1, w2, w3, Xe, We, wnorm, xnorm, best);
  gemm_kernel<<<dim3(42, 64), 256, 0, stream>>>(Xe, We, xnorm, wnorm, best);
  finalize_kernel<<<96, 256, 0, stream>>>(best, (float*)d_out);
}

// Round 6
// 184.269 us; speedup vs baseline: 1.3649x; 1.3649x over previous
//
#include <hip/hip_runtime.h>
#include <stdint.h>

#define DIM 256

typedef int intx4 __attribute__((ext_vector_type(4)));

// i8 quantization: scale S = 5.5/127 (saturating; P(|x|>5.5) ~ 4e-8/elem).
#define SCALE_INV 23.0909090909f   // 127/5.5
#define TWO_S2    0.0037510075f    // 2*(5.5/127)^2
#define BAND      8.0f             // ~10 sigma of screening d2 pair-diff error
#define CAP       128

// Workspace layout (bytes):
//   Xq    : 8192*256 i8  @ 0         (2,097,152)
//   Wq    : 5376*256 i8  @ 2097152   (1,376,256)
//   xnorm : 8192 f32     @ 3473408
//   wnorm : 5376 f32     @ 3506176
//   best  : 24576 u64    @ 3527680   packed (d2_bits<<32)|col  (col level-local)
//   cnt   : 24576 i32    @ 3724288
//   cand  : 24576*128 u16@ 3822592   (6,291,456)
#define WS_WQ_OFF    2097152
#define WS_XNORM_OFF 3473408
#define WS_WNORM_OFF 3506176
#define WS_BEST_OFF  3527680
#define WS_CNT_OFF   3724288
#define WS_CAND_OFF  3822592

#define AS1(p) ((const __attribute__((address_space(1))) void*)(p))
#define AS3(p) ((__attribute__((address_space(3))) void*)(p))

// One wave per row: exact fp32 norm + i8 quantization.
// Blocks 0..95 also init best[] (=~0) and cnt[] (=0).
__global__ __launch_bounds__(256) void conv_kernel(
    const float* __restrict__ x, const float* __restrict__ w1,
    const float* __restrict__ w2, const float* __restrict__ w3,
    unsigned char* __restrict__ Xq, unsigned char* __restrict__ Wq,
    float* __restrict__ wnorm, float* __restrict__ xnorm,
    unsigned long long* __restrict__ best, int* __restrict__ cnt) {
  if (blockIdx.x < 96) {
    best[blockIdx.x * 256 + threadIdx.x] = ~0ull;
    cnt[blockIdx.x * 256 + threadIdx.x] = 0;
  }

  int task = blockIdx.x * 4 + (threadIdx.x >> 6);
  int lane = threadIdx.x & 63;
  const float* src; unsigned char* dst; float* ndst;
  if (task < 8192) {
    src = x + (size_t)task * DIM; dst = Xq + (size_t)task * DIM;
    ndst = xnorm + task;
  } else {
    int wi = task - 8192;
    if (wi < 256)       src = w1 + (size_t)wi * DIM;
    else if (wi < 1280) src = w2 + (size_t)(wi - 256) * DIM;
    else                src = w3 + (size_t)(wi - 1280) * DIM;
    dst = Wq + (size_t)wi * DIM; ndst = wnorm + wi;
  }
  float4 v = *(const float4*)(src + lane * 4);
  float fv[4] = {v.x, v.y, v.z, v.w};
  float s = fv[0]*fv[0] + fv[1]*fv[1] + fv[2]*fv[2] + fv[3]*fv[3];
  #pragma unroll
  for (int o = 32; o > 0; o >>= 1) s += __shfl_xor(s, o);
  if (lane == 0) *ndst = s;

  unsigned char qv[4];
  #pragma unroll
  for (int e = 0; e < 4; ++e) {
    int vi = (int)rintf(fv[e] * SCALE_INV);
    vi = vi < -127 ? -127 : (vi > 127 ? 127 : vi);
    qv[e] = (unsigned char)(signed char)vi;
  }
  *(uchar4*)(dst + lane * 4) = make_uchar4(qv[0], qv[1], qv[2], qv[3]);
}

// i8 screening GEMM, 128x128 tiles, K=256 in 4 chunks of 64.
// grid = (64 row-blocks, 42 col-blocks)  [x = row: same-row col-blocks are
// dispatch-spread, improving the fetched-global-best collection filter].
// Epilogue: per-row argmin (packed u64 atomicMin) then band-collection of
// candidate cols (threshold = post-update global best + BAND; monotone-safe:
// snapshot >= final best, so it can only over-collect).
__global__ __launch_bounds__(256) void gemm_kernel(
    const unsigned char* __restrict__ Xq, const unsigned char* __restrict__ Wq,
    const float* __restrict__ xnorm, const float* __restrict__ wnorm,
    unsigned long long* __restrict__ best, int* __restrict__ cnt,
    unsigned short* __restrict__ cand) {
  __shared__ __align__(16) unsigned char As[8192];  // 128 rows x 64B, swizzled
  __shared__ __align__(16) unsigned char Bs[8192];
  __shared__ unsigned long long red[2][128];
  __shared__ float gthr[128];

  const int rb = blockIdx.x, cb = blockIdx.y;
  const int r0 = rb * 128, n0 = cb * 128;
  int level, lbase;
  if (cb < 2)       { level = 0; lbase = 0; }
  else if (cb < 10) { level = 1; lbase = 256; }
  else              { level = 2; lbase = 1280; }

  const int t = threadIdx.x;
  const int w = t >> 6;
  const int lane = t & 63;
  const int ln = lane & 15, q = lane >> 4;
  const int wm = (w >> 1) * 64, wncol = (w & 1) * 64;

  intx4 acc[4][4];
  #pragma unroll
  for (int i = 0; i < 4; ++i)
    #pragma unroll
    for (int j = 0; j < 4; ++j) acc[i][j] = (intx4)0;

  for (int ch = 0; ch < 4; ++ch) {
    // Stage: 512 slots of 16B per tile; slot(m,kq) = m*4 + (kq ^ (m&3) ^ ((m>>2)&3))
    // -> frag ds_read_b128 is 2-way-conflict max (free).
    #pragma unroll
    for (int it = 0; it < 2; ++it) {
      int p = it * 256 + t;
      int m = p >> 2;
      int kq = (p & 3) ^ (m & 3) ^ ((m >> 2) & 3);
      const unsigned char* ga = Xq + (size_t)(r0 + m) * DIM + ch * 64 + kq * 16;
      const unsigned char* gb = Wq + (size_t)(n0 + m) * DIM + ch * 64 + kq * 16;
      int ldsb = (it * 256 + (t & 192)) * 16;  // wave-uniform byte base
      __builtin_amdgcn_global_load_lds(AS1(ga), AS3(As + ldsb), 16, 0, 0);
      __builtin_amdgcn_global_load_lds(AS1(gb), AS3(Bs + ldsb), 16, 0, 0);
    }
    __syncthreads();
    intx4 a[4], b[4];
    #pragma unroll
    for (int mt = 0; mt < 4; ++mt) {
      int m = wm + mt * 16 + ln;
      int slot = m * 4 + (q ^ (m & 3) ^ ((m >> 2) & 3));
      a[mt] = *(const intx4*)&As[slot * 16];
    }
    #pragma unroll
    for (int nt = 0; nt < 4; ++nt) {
      int n = wncol + nt * 16 + ln;
      int slot = n * 4 + (q ^ (n & 3) ^ ((n >> 2) & 3));
      b[nt] = *(const intx4*)&Bs[slot * 16];
    }
    #pragma unroll
    for (int mt = 0; mt < 4; ++mt)
      #pragma unroll
      for (int nt = 0; nt < 4; ++nt)
        acc[mt][nt] = __builtin_amdgcn_mfma_i32_16x16x64_i8(
            a[mt], b[nt], acc[mt][nt], 0, 0, 0);
    __syncthreads();
  }

  // d2_approx = xn + wn - 2*S^2*dot_i32
  float wnv[4];
  #pragma unroll
  for (int nt = 0; nt < 4; ++nt) wnv[nt] = wnorm[n0 + wncol + nt * 16 + ln];

  // Pass 1: per-row argmin -> atomicMin -> per-row threshold in LDS.
  #pragma unroll
  for (int mt = 0; mt < 4; ++mt) {
    #pragma unroll
    for (int r = 0; r < 4; ++r) {
      int rowl = wm + mt * 16 + q * 4 + r;
      float xnv = xnorm[r0 + rowl];
      unsigned long long bp = ~0ull;
      #pragma unroll
      for (int nt = 0; nt < 4; ++nt) {
        float d2 = fmaxf(xnv + wnv[nt] - TWO_S2 * (float)acc[mt][nt][r], 0.0f);
        unsigned col = (unsigned)(n0 + wncol + nt * 16 + ln - lbase);
        unsigned long long p =
            ((unsigned long long)__float_as_uint(d2) << 32) | col;
        bp = (p < bp) ? p : bp;
      }
      #pragma unroll
      for (int off = 1; off < 16; off <<= 1) {
        unsigned long long o = __shfl_xor(bp, off);
        bp = (o < bp) ? o : bp;
      }
      if (ln == 0) red[w & 1][rowl] = bp;
    }
  }
  __syncthreads();
  if (t < 128) {
    unsigned long long a = red[0][t], b = red[1][t];
    unsigned long long m = (a < b) ? a : b;
    unsigned long long old = atomicMin(&best[level * 8192 + r0 + t], m);
    unsigned long long g = (old < m) ? old : m;  // snapshot >= final best
    gthr[t] = __uint_as_float((unsigned)(g >> 32)) + BAND;
  }
  __syncthreads();

  // Pass 2: collect candidate cols within band.
  #pragma unroll
  for (int mt = 0; mt < 4; ++mt) {
    #pragma unroll
    for (int r = 0; r < 4; ++r) {
      int rowl = wm + mt * 16 + q * 4 + r;
      float xnv = xnorm[r0 + rowl];
      float thr = gthr[rowl];
      #pragma unroll
      for (int nt = 0; nt < 4; ++nt) {
        float d2 = fmaxf(xnv + wnv[nt] - TWO_S2 * (float)acc[mt][nt][r], 0.0f);
        if (d2 < thr) {
          int lr = level * 8192 + r0 + rowl;
          int pos = atomicAdd(&cnt[lr], 1);
          if (pos < CAP)
            cand[(size_t)lr * CAP + pos] =
                (unsigned short)(n0 + wncol + nt * 16 + ln - lbase);
        }
      }
    }
  }
}

// One wave per (level,row): exact fp32 rescore of candidates (plus the
// approx-argmin), tie -> lowest index; emit coords + q = sqrt(d2).
__global__ __launch_bounds__(256) void rescore_kernel(
    const float* __restrict__ x, const float* __restrict__ w1,
    const float* __restrict__ w2, const float* __restrict__ w3,
    const float* __restrict__ xnorm, const float* __restrict__ wnorm,
    const unsigned long long* __restrict__ best, const int* __restrict__ cnt,
    const unsigned short* __restrict__ cand, float* __restrict__ out) {
  int task = blockIdx.x * 4 + (threadIdx.x >> 6);
  int lane = threadIdx.x & 63;
  int level = task >> 13, row = task & 8191;
  const float* wl; unsigned side; int lbase;
  if (level == 0)      { wl = w1; side = 16; lbase = 0; }
  else if (level == 1) { wl = w2; side = 32; lbase = 256; }
  else                 { wl = w3; side = 64; lbase = 1280; }

  float4 xv = *(const float4*)(x + (size_t)row * DIM + lane * 4);
  float xn = xnorm[row];
  int nc = cnt[task]; nc = nc > CAP ? CAP : nc;
  unsigned bidx = (unsigned)(best[task] & 0xFFFFFFFFull);

  unsigned long long bp = ~0ull;
  for (int ci = -1; ci < nc; ++ci) {
    unsigned idx = (ci < 0) ? bidx : (unsigned)cand[(size_t)task * CAP + ci];
    float4 wv = *(const float4*)(wl + (size_t)idx * DIM + lane * 4);
    float p = xv.x*wv.x + xv.y*wv.y + xv.z*wv.z + xv.w*wv.w;
    #pragma unroll
    for (int o = 32; o > 0; o >>= 1) p += __shfl_xor(p, o);
    float d2 = fmaxf(xn + wnorm[lbase + idx] - 2.0f * p, 0.0f);
    unsigned long long pk =
        ((unsigned long long)__float_as_uint(d2) << 32) | idx;
    bp = (pk < bp) ? pk : bp;
  }
  if (lane == 0) {
    unsigned idx = (unsigned)(bp & 0xFFFFFFFFull);
    float d2 = __uint_as_float((unsigned)(bp >> 32));
    out[level * 16384 + row * 2 + 0] = (float)(idx / side);
    out[level * 16384 + row * 2 + 1] = (float)(idx % side);
    out[49152 + level * 8192 + row] = sqrtf(d2);
  }
}

extern "C" void kernel_launch(void* const* d_in, const int* in_sizes, int n_in,
                              void* d_out, int out_size, void* d_ws, size_t ws_size,
                              hipStream_t stream) {
  const float* x  = (const float*)d_in[0];
  const float* w1 = (const float*)d_in[1];
  const float* w2 = (const float*)d_in[2];
  const float* w3 = (const float*)d_in[3];
  unsigned char* Xq = (unsigned char*)d_ws;
  unsigned char* Wq = (unsigned char*)((char*)d_ws + WS_WQ_OFF);
  float* xnorm = (float*)((char*)d_ws + WS_XNORM_OFF);
  float* wnorm = (float*)((char*)d_ws + WS_WNORM_OFF);
  unsigned long long* best = (unsigned long long*)((char*)d_ws + WS_BEST_OFF);
  int* cnt = (int*)((char*)d_ws + WS_CNT_OFF);
  unsigned short* cand = (unsigned short*)((char*)d_ws + WS_CAND_OFF);

  conv_kernel<<<3392, 256, 0, stream>>>(x, w1, w2, w3, Xq, Wq, wnorm, xnorm,
                                        best, cnt);
  gemm_kernel<<<dim3(64, 42), 256, 0, stream>>>(Xq, Wq, xnorm, wnorm, best,
                                                cnt, cand);
  rescore_kernel<<<6144, 256, 0, stream>>>(x, w1, w2, w3, xnorm, wnorm, best,
                                           cnt, cand, (float*)d_out);
}

// Round 7
// 170.241 us; speedup vs baseline: 1.4774x; 1.0824x over previous
//
#include <hip/hip_runtime.h>
#include <stdint.h>

#define DIM 256

typedef int intx4 __attribute__((ext_vector_type(4)));

// i8 quantization: scale S = 5.5/127 (saturating; P(|x|>5.5) ~ 4e-8/elem).
#define SCALE_INV 23.0909090909f   // 127/5.5
#define TWO_S2    0.0037510075f    // 2*(5.5/127)^2
#define BAND      8.0f             // ~10 sigma of screening d2 pair-diff error
#define NCAND     6

// Workspace layout (bytes):
//   Xq    : 8192*256 i8   @ 0         (2,097,152)
//   Wq    : 5376*256 i8   @ 2097152   (1,376,256)
//   xnorm : 8192 f32      @ 3473408
//   wnorm : 5376 f32      @ 3506176
//   part  : 344064 u64    @ 3527680   (2,752,512) private per-(block,row) slots
//   cand  : 344064*6 u32  @ 6280192   (8,257,536)
// part/cand slot base: L0 row*2+cbl | 16384+row*8+cbl | 81920+row*32+cbl
#define WS_WQ_OFF    2097152
#define WS_XNORM_OFF 3473408
#define WS_WNORM_OFF 3506176
#define WS_PART_OFF  3527680
#define WS_CAND_OFF  6280192

#define AS1(p) ((const __attribute__((address_space(1))) void*)(p))
#define AS3(p) ((__attribute__((address_space(3))) void*)(p))

// One wave per row: exact fp32 norm + i8 quantization. No init needed:
// part[] slots are all unconditionally written by gemm.
__global__ __launch_bounds__(256) void conv_kernel(
    const float* __restrict__ x, const float* __restrict__ w1,
    const float* __restrict__ w2, const float* __restrict__ w3,
    unsigned char* __restrict__ Xq, unsigned char* __restrict__ Wq,
    float* __restrict__ wnorm, float* __restrict__ xnorm) {
  int task = blockIdx.x * 4 + (threadIdx.x >> 6);
  int lane = threadIdx.x & 63;
  const float* src; unsigned char* dst; float* ndst;
  if (task < 8192) {
    src = x + (size_t)task * DIM; dst = Xq + (size_t)task * DIM;
    ndst = xnorm + task;
  } else {
    int wi = task - 8192;
    if (wi < 256)       src = w1 + (size_t)wi * DIM;
    else if (wi < 1280) src = w2 + (size_t)(wi - 256) * DIM;
    else                src = w3 + (size_t)(wi - 1280) * DIM;
    dst = Wq + (size_t)wi * DIM; ndst = wnorm + wi;
  }
  float4 v = *(const float4*)(src + lane * 4);
  float fv[4] = {v.x, v.y, v.z, v.w};
  float s = fv[0]*fv[0] + fv[1]*fv[1] + fv[2]*fv[2] + fv[3]*fv[3];
  #pragma unroll
  for (int o = 32; o > 0; o >>= 1) s += __shfl_xor(s, o);
  if (lane == 0) *ndst = s;

  unsigned char qv[4];
  #pragma unroll
  for (int e = 0; e < 4; ++e) {
    int vi = (int)rintf(fv[e] * SCALE_INV);
    vi = vi < -127 ? -127 : (vi > 127 ? 127 : vi);
    qv[e] = (unsigned char)(signed char)vi;
  }
  *(uchar4*)(dst + lane * 4) = make_uchar4(qv[0], qv[1], qv[2], qv[3]);
}

// i8 screening GEMM, 128x128 tiles, K=256 in 4 chunks of 64.
// ZERO global atomics: per-block results go to private part[]/cand[] slots
// (plain stores); in-block coordination via LDS only. Band filter uses the
// block-LOCAL min + BAND (superset of global band since lmin_cb >= g).
__global__ __launch_bounds__(256) void gemm_kernel(
    const unsigned char* __restrict__ Xq, const unsigned char* __restrict__ Wq,
    const float* __restrict__ xnorm, const float* __restrict__ wnorm,
    unsigned long long* __restrict__ part, unsigned int* __restrict__ cand) {
  __shared__ __align__(16) unsigned char As[8192];  // 128 rows x 64B, swizzled
  __shared__ __align__(16) unsigned char Bs[8192];
  __shared__ unsigned long long red[2][128];
  __shared__ float gthr[128];
  __shared__ int scnt[128];

  const int rb = blockIdx.x, cb = blockIdx.y;
  const int r0 = rb * 128, n0 = cb * 128;
  int ncb, cbl, sbase0;
  if (cb < 2)       { ncb = 2;  cbl = cb;      sbase0 = 0; }
  else if (cb < 10) { ncb = 8;  cbl = cb - 2;  sbase0 = 16384; }
  else              { ncb = 32; cbl = cb - 10; sbase0 = 81920; }
  const int c0 = cbl * 128;  // level-local col base

  const int t = threadIdx.x;
  const int w = t >> 6;
  const int lane = t & 63;
  const int ln = lane & 15, q = lane >> 4;
  const int wm = (w >> 1) * 64, wncol = (w & 1) * 64;

  intx4 acc[4][4];
  #pragma unroll
  for (int i = 0; i < 4; ++i)
    #pragma unroll
    for (int j = 0; j < 4; ++j) acc[i][j] = (intx4)0;

  for (int ch = 0; ch < 4; ++ch) {
    #pragma unroll
    for (int it = 0; it < 2; ++it) {
      int p = it * 256 + t;
      int m = p >> 2;
      int kq = (p & 3) ^ (m & 3) ^ ((m >> 2) & 3);
      const unsigned char* ga = Xq + (size_t)(r0 + m) * DIM + ch * 64 + kq * 16;
      const unsigned char* gb = Wq + (size_t)(n0 + m) * DIM + ch * 64 + kq * 16;
      int ldsb = (it * 256 + (t & 192)) * 16;  // wave-uniform byte base
      __builtin_amdgcn_global_load_lds(AS1(ga), AS3(As + ldsb), 16, 0, 0);
      __builtin_amdgcn_global_load_lds(AS1(gb), AS3(Bs + ldsb), 16, 0, 0);
    }
    __syncthreads();
    intx4 a[4], b[4];
    #pragma unroll
    for (int mt = 0; mt < 4; ++mt) {
      int m = wm + mt * 16 + ln;
      int slot = m * 4 + (q ^ (m & 3) ^ ((m >> 2) & 3));
      a[mt] = *(const intx4*)&As[slot * 16];
    }
    #pragma unroll
    for (int nt = 0; nt < 4; ++nt) {
      int n = wncol + nt * 16 + ln;
      int slot = n * 4 + (q ^ (n & 3) ^ ((n >> 2) & 3));
      b[nt] = *(const intx4*)&Bs[slot * 16];
    }
    #pragma unroll
    for (int mt = 0; mt < 4; ++mt)
      #pragma unroll
      for (int nt = 0; nt < 4; ++nt)
        acc[mt][nt] = __builtin_amdgcn_mfma_i32_16x16x64_i8(
            a[mt], b[nt], acc[mt][nt], 0, 0, 0);
    __syncthreads();
  }

  // d2_approx = xn + wn - 2*S^2*dot_i32
  float wnv[4];
  #pragma unroll
  for (int nt = 0; nt < 4; ++nt) wnv[nt] = wnorm[n0 + wncol + nt * 16 + ln];

  // Pass 1: per-row block-local argmin (LDS exchange between the 2 waves
  // covering each row's two col-halves; no global traffic).
  #pragma unroll
  for (int mt = 0; mt < 4; ++mt) {
    #pragma unroll
    for (int r = 0; r < 4; ++r) {
      int rowl = wm + mt * 16 + q * 4 + r;
      float xnv = xnorm[r0 + rowl];
      unsigned long long bp = ~0ull;
      #pragma unroll
      for (int nt = 0; nt < 4; ++nt) {
        float d2 = fmaxf(xnv + wnv[nt] - TWO_S2 * (float)acc[mt][nt][r], 0.0f);
        unsigned col = (unsigned)(c0 + wncol + nt * 16 + ln);
        unsigned long long p =
            ((unsigned long long)__float_as_uint(d2) << 32) | col;
        bp = (p < bp) ? p : bp;
      }
      #pragma unroll
      for (int off = 1; off < 16; off <<= 1) {
        unsigned long long o = __shfl_xor(bp, off);
        bp = (o < bp) ? o : bp;
      }
      if (ln == 0) red[w & 1][rowl] = bp;
    }
  }
  __syncthreads();
  unsigned long long mkeep = ~0ull;
  if (t < 128) {
    unsigned long long a = red[0][t], b = red[1][t];
    mkeep = (a < b) ? a : b;
    gthr[t] = __uint_as_float((unsigned)(mkeep >> 32)) + BAND;
    scnt[t] = 0;
  }
  __syncthreads();

  // Pass 2: collect candidates within block-local band into private slots.
  #pragma unroll
  for (int mt = 0; mt < 4; ++mt) {
    #pragma unroll
    for (int r = 0; r < 4; ++r) {
      int rowl = wm + mt * 16 + q * 4 + r;
      float xnv = xnorm[r0 + rowl];
      float thr = gthr[rowl];
      #pragma unroll
      for (int nt = 0; nt < 4; ++nt) {
        float d2 = fmaxf(xnv + wnv[nt] - TWO_S2 * (float)acc[mt][nt][r], 0.0f);
        if (d2 < thr) {
          int pos = atomicAdd(&scnt[rowl], 1);  // LDS atomic: block-private
          if (pos < NCAND) {
            size_t sb = sbase0 + (size_t)(r0 + rowl) * ncb + cbl;
            cand[sb * NCAND + pos] =
                (__float_as_uint(d2) & 0xFFFF0000u) |
                (unsigned)(c0 + wncol + nt * 16 + ln);
          }
        }
      }
    }
  }
  __syncthreads();
  if (t < 128) {
    int c = scnt[t]; c = c > NCAND ? NCAND : c;
    part[sbase0 + (size_t)(r0 + t) * ncb + cbl] =
        mkeep | ((unsigned long long)c << 16);
  }
}

// One wave per (level,row): read private partials (no atomics), wave-min ->
// global screening best g; exact fp32 rescore of each qualifying block's
// argmin + pruned list entries; tie -> lowest index; emit coords + sqrt(d2).
__global__ __launch_bounds__(256) void rescore_kernel(
    const float* __restrict__ x, const float* __restrict__ w1,
    const float* __restrict__ w2, const float* __restrict__ w3,
    const float* __restrict__ xnorm, const float* __restrict__ wnorm,
    const unsigned long long* __restrict__ part,
    const unsigned int* __restrict__ cand, float* __restrict__ out) {
  int task = blockIdx.x * 4 + (threadIdx.x >> 6);
  int lane = threadIdx.x & 63;
  int level = task >> 13, row = task & 8191;
  const float* wl; unsigned side; int lbw, ncb, sbase0;
  if (level == 0)      { wl = w1; side = 16; lbw = 0;    ncb = 2;  sbase0 = 0; }
  else if (level == 1) { wl = w2; side = 32; lbw = 256;  ncb = 8;  sbase0 = 16384; }
  else                 { wl = w3; side = 64; lbw = 1280; ncb = 32; sbase0 = 81920; }
  size_t sbr = sbase0 + (size_t)row * ncb;

  unsigned long long pm = (lane < ncb) ? part[sbr + lane] : ~0ull;
  unsigned long long gm = pm;
  #pragma unroll
  for (int off = 1; off < 64; off <<= 1) {
    unsigned long long o = __shfl_xor(gm, off);
    gm = (o < gm) ? o : gm;
  }
  float thr = __uint_as_float((unsigned)(gm >> 32)) + BAND;

  float4 xv = *(const float4*)(x + (size_t)row * DIM + lane * 4);
  float xn = xnorm[row];
  unsigned long long bestpk = ~0ull;

  auto resc = [&](unsigned idx) {
    float4 wv = *(const float4*)(wl + (size_t)idx * DIM + lane * 4);
    float p = xv.x*wv.x + xv.y*wv.y + xv.z*wv.z + xv.w*wv.w;
    #pragma unroll
    for (int o = 32; o > 0; o >>= 1) p += __shfl_xor(p, o);
    float d2e = fmaxf(xn + wnorm[lbw + idx] - 2.0f * p, 0.0f);
    unsigned long long pk =
        ((unsigned long long)__float_as_uint(d2e) << 32) | idx;
    bestpk = (pk < bestpk) ? pk : bestpk;
  };

  for (int cbi = 0; cbi < ncb; ++cbi) {
    unsigned long long p = __shfl(pm, cbi);
    if (__uint_as_float((unsigned)(p >> 32)) >= thr) continue;
    unsigned pcol = (unsigned)(p & 0xFFFu);
    resc(pcol);
    int c = (int)((p >> 16) & 0xFFu);
    for (int j = 0; j < c; ++j) {
      unsigned e = cand[(sbr + cbi) * NCAND + j];  // wave-uniform broadcast
      unsigned ecol = e & 0xFFFu;
      if (ecol == pcol) continue;
      if (__uint_as_float(e & 0xFFFF0000u) >= thr) continue;
      resc(ecol);
    }
  }

  if (lane == 0) {
    unsigned idx = (unsigned)(bestpk & 0xFFFFFFFFull);
    float d2 = __uint_as_float((unsigned)(bestpk >> 32));
    out[level * 16384 + row * 2 + 0] = (float)(idx / side);
    out[level * 16384 + row * 2 + 1] = (float)(idx % side);
    out[49152 + level * 8192 + row] = sqrtf(d2);
  }
}

extern "C" void kernel_launch(void* const* d_in, const int* in_sizes, int n_in,
                              void* d_out, int out_size, void* d_ws, size_t ws_size,
                              hipStream_t stream) {
  const float* x  = (const float*)d_in[0];
  const float* w1 = (const float*)d_in[1];
  const float* w2 = (const float*)d_in[2];
  const float* w3 = (const float*)d_in[3];
  unsigned char* Xq = (unsigned char*)d_ws;
  unsigned char* Wq = (unsigned char*)((char*)d_ws + WS_WQ_OFF);
  float* xnorm = (float*)((char*)d_ws + WS_XNORM_OFF);
  float* wnorm = (float*)((char*)d_ws + WS_WNORM_OFF);
  unsigned long long* part = (unsigned long long*)((char*)d_ws + WS_PART_OFF);
  unsigned int* cand = (unsigned int*)((char*)d_ws + WS_CAND_OFF);

  conv_kernel<<<3392, 256, 0, stream>>>(x, w1, w2, w3, Xq, Wq, wnorm, xnorm);
  gemm_kernel<<<dim3(64, 42), 256, 0, stream>>>(Xq, Wq, xnorm, wnorm, part, cand);
  rescore_kernel<<<6144, 256, 0, stream>>>(x, w1, w2, w3, xnorm, wnorm, part,
                                           cand, (float*)d_out);
}